// Round 11
// baseline (369.195 us; speedup 1.0000x reference)
//
#include <hip/hip_runtime.h>

#define NB 4096
#define MD 100
#define ND 80
#define LI 10
#define NIT 10
#define MT 10   // m-rows per LDS tile
#define WPB 4   // waves (batches) per block

// in-wave replacement for __syncthreads(): drain LDS ops, fence the compiler.
#define WAVE_SYNC() asm volatile("s_waitcnt lgkmcnt(0)" ::: "memory")

__global__ void zero_loss_k(float* out) {
    if (threadIdx.x == 0) out[(size_t)NB * ND] = 0.f;
}

__device__ __forceinline__ float fast_tanh(float a) {
    float e = __builtin_amdgcn_exp2f(a * 2.885390082f);
    return 1.f - 2.f * __builtin_amdgcn_rcpf(e + 1.f);
}

__global__ __launch_bounds__(64 * WPB, 1) void admm_k(
    const float* __restrict__ x_ini, const float* __restrict__ y,
    const float* __restrict__ H,     const float* __restrict__ xt,
    const float* __restrict__ ILb,   const float* __restrict__ tauA,
    const float* __restrict__ g1A,   const float* __restrict__ g3A,
    float* __restrict__ out)
{
    __shared__ __align__(16) float Hs[WPB][MT * ND];   // 4 x 3200 B
    __shared__ __align__(16) float ys[WPB][MD + 4];
    __shared__ __align__(16) float xb[WPB][2][ND];

    const int w  = threadIdx.x >> 6;   // wave id = batch slot
    const int l  = threadIdx.x & 63;   // lane
    const int b  = blockIdx.x * WPB + w;
    const int r0 = l >> 2;   // 0..15
    const int s4 = l & 3;    // 0..3  -> col slice [20*s4, 20*s4+20)

    // ---- stage y (100 floats) ----
    if (l < MD / 4)
        ((float4*)ys[w])[l] = ((const float4*)(y + (size_t)b * MD))[l];

    // ---- build HTH rows into registers + HTy, tile-by-tile ----
    float A[5][20];
    float hty[5];
    #pragma unroll
    for (int g = 0; g < 5; ++g) {
        hty[g] = 0.f;
        #pragma unroll
        for (int c = 0; c < 20; ++c) A[g][c] = 0.f;
    }

    const float* Hg = H + (size_t)b * (MD * ND);
    for (int t = 0; t < MD / MT; ++t) {
        WAVE_SYNC();  // previous tile fully consumed (WAR) / ys staged at t=0
        {
            const float4* src = (const float4*)(Hg + t * MT * ND);  // 200 float4
            float4* dst = (float4*)Hs[w];
            float4 v0 = src[l], v1 = src[64 + l], v2 = src[128 + l];
            dst[l] = v0; dst[64 + l] = v1; dst[128 + l] = v2;
            if (l < 8) dst[192 + l] = src[192 + l];
        }
        WAVE_SYNC();  // staging visible before consumption (RAW)
        #pragma unroll
        for (int mm = 0; mm < MT; ++mm) {
            const float yv = ys[w][t * MT + mm];
            float cv[5];
            #pragma unroll
            for (int g = 0; g < 5; ++g) cv[g] = Hs[w][mm * ND + r0 + 16 * g];
            #pragma unroll
            for (int j = 0; j < 5; ++j) {
                const float4 rv = *(const float4*)&Hs[w][mm * ND + s4 * 20 + 4 * j];
                #pragma unroll
                for (int g = 0; g < 5; ++g) {
                    A[g][4 * j + 0] = fmaf(cv[g], rv.x, A[g][4 * j + 0]);
                    A[g][4 * j + 1] = fmaf(cv[g], rv.y, A[g][4 * j + 1]);
                    A[g][4 * j + 2] = fmaf(cv[g], rv.z, A[g][4 * j + 2]);
                    A[g][4 * j + 3] = fmaf(cv[g], rv.w, A[g][4 * j + 3]);
                }
            }
            #pragma unroll
            for (int g = 0; g < 5; ++g) hty[g] = fmaf(cv[g], yv, hty[g]);
        }
    }

    // ---- Gershgorin bound on lambda_max(HTH), fully in-wave ----
    float mx;
    {
        float rs[5];
        #pragma unroll
        for (int g = 0; g < 5; ++g) {
            float s = 0.f;
            #pragma unroll
            for (int c = 0; c < 20; ++c) s += fabsf(A[g][c]);
            rs[g] = s;
        }
        #pragma unroll
        for (int g = 0; g < 5; ++g) {
            rs[g] += __shfl_xor(rs[g], 1);
            rs[g] += __shfl_xor(rs[g], 2);
        }
        mx = rs[0];
        #pragma unroll
        for (int g = 1; g < 5; ++g) mx = fmaxf(mx, rs[g]);
        #pragma unroll
        for (int off = 4; off < 64; off <<= 1) mx = fmaxf(mx, __shfl_xor(mx, off));
    }
    const float lam = mx;

    // ---- ADMM state (per-row, duplicated across the s4 quartet) ----
    float xr[5], zr[5], ur[5];
    #pragma unroll
    for (int g = 0; g < 5; ++g) {
        const float v = x_ini[(size_t)b * ND + r0 + 16 * g];
        xr[g] = v; zr[g] = v; ur[g] = 0.f;
    }

    int par = 0;
    // matvec: acc[g] = (HTH * xb[w][par])[r0+16g]
    auto matvec = [&](float (&acc)[5]) {
        const float* xp = &xb[w][par][0];
        {
            const float4 v = *(const float4*)&xp[s4 * 20];
            #pragma unroll
            for (int g = 0; g < 5; ++g)
                acc[g] = fmaf(A[g][3], v.w, fmaf(A[g][2], v.z,
                         fmaf(A[g][1], v.y, A[g][0] * v.x)));
        }
        #pragma unroll
        for (int j = 1; j < 5; ++j) {
            const float4 v = *(const float4*)&xp[s4 * 20 + 4 * j];
            #pragma unroll
            for (int g = 0; g < 5; ++g) {
                acc[g] = fmaf(A[g][4 * j + 0], v.x, acc[g]);
                acc[g] = fmaf(A[g][4 * j + 1], v.y, acc[g]);
                acc[g] = fmaf(A[g][4 * j + 2], v.z, acc[g]);
                acc[g] = fmaf(A[g][4 * j + 3], v.w, acc[g]);
            }
        }
        #pragma unroll
        for (int g = 0; g < 5; ++g) {
            acc[g] += __shfl_xor(acc[g], 1);
            acc[g] += __shfl_xor(acc[g], 2);
        }
    };

    for (int ii = 0; ii < LI; ++ii) {
        const float tau = tauA[ii];
        const float ilb = ILb[ii];
        const float g1s = 0.5f / g1A[ii];
        const float g3s = 0.5f / g3A[ii];
        const float delta = 0.5f * lam;
        const float theta = tau + delta;
        const float sigma = theta / delta;
        const float invth = 1.f / theta;
        const float twod  = 2.f / delta;

        float rres[5], dk[5], acc[5];

        // r0 = b - A*x (warm start)
        if (s4 == 0) {
            #pragma unroll
            for (int g = 0; g < 5; ++g) xb[w][par][r0 + 16 * g] = xr[g];
        }
        WAVE_SYNC();
        matvec(acc);
        #pragma unroll
        for (int g = 0; g < 5; ++g) {
            rres[g] = (hty[g] + ur[g] + tau * zr[g]) - (acc[g] + tau * xr[g]);
            dk[g] = rres[g] * invth;
        }
        par ^= 1;
        float rho = delta / theta;

        for (int k = 1; k < NIT; ++k) {
            #pragma unroll
            for (int g = 0; g < 5; ++g) xr[g] += dk[g];
            if (s4 == 0) {
                #pragma unroll
                for (int g = 0; g < 5; ++g) xb[w][par][r0 + 16 * g] = dk[g];
            }
            WAVE_SYNC();
            matvec(acc);
            #pragma unroll
            for (int g = 0; g < 5; ++g) rres[g] -= acc[g] + tau * dk[g];
            const float rhon = 1.f / (2.f * sigma - rho);
            #pragma unroll
            for (int g = 0; g < 5; ++g) dk[g] = rhon * (rho * dk[g] + twod * rres[g]);
            rho = rhon;
            par ^= 1;
        }
        #pragma unroll
        for (int g = 0; g < 5; ++g) xr[g] += dk[g];

        // z, u updates
        #pragma unroll
        for (int g = 0; g < 5; ++g) {
            const float tt = xr[g] - ur[g] * ilb;
            zr[g] = fast_tanh(tt * g1s) + fast_tanh((tt - 2.f) * g3s)
                  + fast_tanh((tt + 2.f) * g3s);
            ur[g] = fmaf(tau, zr[g] - xr[g], ur[g]);
        }
    }

    // ---- epilogue: x out + per-wave loss reduce ----
    float lv = 0.f;
    #pragma unroll
    for (int g = 0; g < 5; ++g) {
        const float xtr = xt[(size_t)b * ND + r0 + 16 * g];
        const float dx = xr[g] - xtr, dz = zr[g] - xtr;
        lv += dx * dx + dz * dz;
        if (s4 == 0) out[(size_t)b * ND + r0 + 16 * g] = xr[g];
    }
    if (s4 != 0) lv = 0.f;
    #pragma unroll
    for (int off = 1; off < 64; off <<= 1) lv += __shfl_xor(lv, off);
    if (l == 0) atomicAdd(out + (size_t)NB * ND, lv);
}

extern "C" void kernel_launch(void* const* d_in, const int* in_sizes, int n_in,
                              void* d_out, int out_size, void* d_ws, size_t ws_size,
                              hipStream_t stream) {
    const float* x_ini = (const float*)d_in[0];
    const float* y     = (const float*)d_in[1];
    const float* H     = (const float*)d_in[2];
    const float* xt    = (const float*)d_in[3];
    const float* ILb   = (const float*)d_in[4];
    const float* tauA  = (const float*)d_in[5];
    const float* g1A   = (const float*)d_in[6];
    const float* g3A   = (const float*)d_in[7];
    float* out = (float*)d_out;

    zero_loss_k<<<1, 64, 0, stream>>>(out);
    admm_k<<<NB / WPB, 64 * WPB, 0, stream>>>(x_ini, y, H, xt, ILb, tauA, g1A, g3A, out);
}